// Round 2
// baseline (459.976 us; speedup 1.0000x reference)
//
#include <hip/hip_runtime.h>

// ChunkedSelfAttention (RoPE + per-chunk causal SDPA), MI355X gfx950.
// R2: software-pipelined staging (T14), double-buffered LDS, in-register P
// via v_permlane32_swap (T12), XOR-swizzled V^T staging, half-diagonal skip.

typedef __attribute__((ext_vector_type(2)))  float     f32x2;
typedef __attribute__((ext_vector_type(4)))  float     f32x4;
typedef __attribute__((ext_vector_type(16))) float     f32x16;
typedef __attribute__((ext_vector_type(8)))  _Float16  f16x8;
typedef unsigned int   u32;
typedef unsigned short u16;
typedef __attribute__((ext_vector_type(4))) unsigned int u32x4;

#define MFMA(a, b, c) __builtin_amdgcn_mfma_f32_32x32x16_f16(a, b, c, 0, 0, 0)

constexpr int Ll = 4096;
// scale(1/sqrt(128)) * log2(e): softmax in base-2 (exp2) domain.
constexpr float QSCALE = 0.08838834764831845f * 1.4426950408889634f;

// ---- per-buffer LDS layout (bytes): KH [64][136], KL same; VT hi/lo [128][72] ----
#define KH_OFF   0
#define KL_OFF   17408
#define VTH_OFF  34816
#define VTL_OFF  53248
#define BUF_SZ   71680
#define SMEM_SZ  (2 * BUF_SZ)   // 140 KiB, double-buffered

__device__ __forceinline__ f16x8 ld_f16x8(const void* p) { f16x8 v; __builtin_memcpy(&v, p, 16); return v; }
__device__ __forceinline__ f32x4 ld_f32x4(const void* p) { f32x4 v; __builtin_memcpy(&v, p, 16); return v; }
__device__ __forceinline__ f32x2 ld_f32x2(const void* p) { f32x2 v; __builtin_memcpy(&v, p, 8);  return v; }

__device__ __forceinline__ u32 packh(_Float16 a, _Float16 b) {
  return (u32)__builtin_bit_cast(u16, a) | ((u32)__builtin_bit_cast(u16, b) << 16);
}
// split fp32 -> f16 hi + f16 lo (residual), two values packed per u32
__device__ __forceinline__ void split2(float a, float b, u32& hp, u32& lp) {
  _Float16 ha = (_Float16)a, hb = (_Float16)b;
  _Float16 la = (_Float16)(a - (float)ha), lb = (_Float16)(b - (float)hb);
  hp = packh(ha, hb);
  lp = packh(la, lb);
}

// ---- cos/sin table: tab[t*64+hid] = {cos, sin} of ang = (t+start)*inv_freq ----
__global__ void rope_table_k(const int* __restrict__ startp, float* __restrict__ tab) {
  int idx = blockIdx.x * 256 + threadIdx.x;         // 4096*64 entries
  int t = idx >> 6, hid = idx & 63;
  float a = (float)hid * (-0.14391156831212878f);
  float invf = expf(a);
  float ang = (float)(t + startp[0]) * invf;
  tab[2 * idx]     = cosf(ang);
  tab[2 * idx + 1] = sinf(ang);
}

__global__ __launch_bounds__(512, 2)
void chunked_attn_k(const float* __restrict__ Qg, const float* __restrict__ Kg,
                    const float* __restrict__ Vg, float* __restrict__ Og,
                    const float* __restrict__ tab) {
  __shared__ __align__(16) unsigned char smem[SMEM_SZ];

  const int bx  = blockIdx.x;
  const int qi  = 3 - (bx & 3);          // q-tile (heavy tiles first)
  const int h   = (bx >> 2) & 15;
  const int c   = (bx >> 6) & 3;
  const int b   = bx >> 8;
  const int tid = threadIdx.x;
  const int w   = tid >> 6;              // wave 0..7
  const int lane= tid & 63;
  const int l31 = lane & 31;
  const int lg2 = lane >> 5;

  const size_t cbase = (size_t)(b * Ll + c * 1024);   // token base of this chunk
  const size_t hoff  = (size_t)h * 128;

  // ---------- Q prologue: 32 q-rows/wave in registers, rope+scale+split ----------
  const int qrow = qi * 256 + w * 32 + l31;
  const float* qbase = Qg + (cbase + qrow) * 2048 + hoff;

  float xq[8][8];
  #pragma unroll
  for (int ds = 0; ds < 8; ++ds) {
    const float* p = qbase + ds * 16 + lg2 * 8;
    f32x4 v0 = ld_f32x4(p);
    f32x4 v1 = ld_f32x4(p + 4);
    xq[ds][0]=v0.x; xq[ds][1]=v0.y; xq[ds][2]=v0.z; xq[ds][3]=v0.w;
    xq[ds][4]=v1.x; xq[ds][5]=v1.y; xq[ds][6]=v1.z; xq[ds][7]=v1.w;
  }
  const float* trowq = tab + (size_t)(c * 1024 + qrow) * 128 + lg2 * 16;
  #pragma unroll
  for (int ds = 0; ds < 4; ++ds) {
    #pragma unroll
    for (int i2 = 0; i2 < 4; ++i2) {
      f32x4 cs = ld_f32x4(trowq + ds * 32 + i2 * 4);  // c0,s0,c1,s1
      int i0 = 2 * i2;
      float a0 = xq[ds][i0],     b0 = xq[ds + 4][i0];
      xq[ds][i0]     = a0 * cs.x - b0 * cs.y;
      xq[ds + 4][i0] = b0 * cs.x + a0 * cs.y;
      float a1 = xq[ds][i0 + 1], b1 = xq[ds + 4][i0 + 1];
      xq[ds][i0 + 1]     = a1 * cs.z - b1 * cs.w;
      xq[ds + 4][i0 + 1] = b1 * cs.z + a1 * cs.w;
    }
  }
  f16x8 qh[8], ql[8];
  #pragma unroll
  for (int ds = 0; ds < 8; ++ds) {
    #pragma unroll
    for (int i = 0; i < 8; ++i) {
      float sv = xq[ds][i] * QSCALE;
      _Float16 hh = (_Float16)sv;
      qh[ds][i] = hh;
      ql[ds][i] = (_Float16)(sv - (float)hh);
    }
  }

  // ---------- state ----------
  f32x16 O[4];
  #pragma unroll
  for (int n = 0; n < 4; ++n) O[n] = (f32x16)0.0f;
  float m2 = -1e30f, lsum = 0.0f;
  const int jmax   = 4 * qi + (w >> 1);
  const int ntiles = 4 * (qi + 1);

  // ---------- staging: register prefetch + transform/store ----------
  f32x2 pka[4], pkb[4], pva[4], pvb[4];

  auto issue = [&](int j) {
    const float* kb_ = Kg + (cbase + (size_t)j * 64) * 2048 + hoff;
    const float* vb_ = Vg + (cbase + (size_t)j * 64) * 2048 + hoff;
    #pragma unroll
    for (int it = 0; it < 4; ++it) {
      int s = tid + it * 512;
      int kk = s >> 5, dh2 = s & 31;
      const float* kr = kb_ + (size_t)kk * 2048 + 2 * dh2;
      pka[it] = ld_f32x2(kr);
      pkb[it] = ld_f32x2(kr + 64);
      int dv2 = s & 63, kp = s >> 6;
      const float* vr = vb_ + (size_t)(2 * kp) * 2048 + 2 * dv2;
      pva[it] = ld_f32x2(vr);
      pvb[it] = ld_f32x2(vr + 2048);
    }
  };

  auto xform = [&](int j, unsigned char* buf) {
    u32* KHu  = (u32*)(buf + KH_OFF);
    u32* KLu  = (u32*)(buf + KL_OFF);
    u32* VTHu = (u32*)(buf + VTH_OFF);
    u32* VTLu = (u32*)(buf + VTL_OFF);
    #pragma unroll
    for (int it = 0; it < 4; ++it) {
      int s = tid + it * 512;
      int kk = s >> 5, dh2 = s & 31;
      f32x4 cs = ld_f32x4(tab + (size_t)(c * 1024 + j * 64 + kk) * 128 + 4 * dh2);
      f32x2 a = pka[it], bb = pkb[it];
      float ar0 = a.x * cs.x - bb.x * cs.y;
      float br0 = bb.x * cs.x + a.x * cs.y;
      float ar1 = a.y * cs.z - bb.y * cs.w;
      float br1 = bb.y * cs.z + a.y * cs.w;
      u32 hp, lp;
      split2(ar0, ar1, hp, lp);
      KHu[kk * 68 + dh2] = hp;       KLu[kk * 68 + dh2] = lp;
      split2(br0, br1, hp, lp);
      KHu[kk * 68 + 32 + dh2] = hp;  KLu[kk * 68 + 32 + dh2] = lp;
      // V^T, XOR-swizzled: dword col kp ^ ((row&56)>>1)
      int dv2 = s & 63, kp = s >> 6;
      int d0 = 2 * dv2;
      int kpS = kp ^ ((d0 & 56) >> 1);
      u32 h0_, l0_, h1_, l1_;
      split2(pva[it].x, pvb[it].x, h0_, l0_);
      split2(pva[it].y, pvb[it].y, h1_, l1_);
      VTHu[d0 * 36 + kpS] = h0_;        VTLu[d0 * 36 + kpS] = l0_;
      VTHu[(d0 + 1) * 36 + kpS] = h1_;  VTLu[(d0 + 1) * 36 + kpS] = l1_;
    }
  };

  issue(0);
  xform(0, smem);
  __syncthreads();

  for (int j = 0; j < ntiles; ++j) {
    unsigned char* bufc = smem + (size_t)(j & 1) * BUF_SZ;
    const bool more = (j + 1 < ntiles);
    if (more) issue(j + 1);        // global loads fly under compute

    if (j <= jmax) {
      const bool full = !((j == jmax) && ((w & 1) == 0));  // even-w diagonal: upper k-half fully masked
      const unsigned char* khb = bufc + KH_OFF + (size_t)l31 * 272 + lg2 * 16;
      const unsigned char* klb = bufc + KL_OFF + (size_t)l31 * 272 + lg2 * 16;

      // ---- QK^T (swapped): S^T[k][q], 3-term f16 split ----
      f32x16 S0 = (f32x16)0.0f, S1 = (f32x16)0.0f;
      #pragma unroll
      for (int ds = 0; ds < 8; ++ds) {
        f16x8 kh0 = ld_f16x8(khb + ds * 32);
        f16x8 kl0 = ld_f16x8(klb + ds * 32);
        S0 = MFMA(kh0, qh[ds], S0);
        S0 = MFMA(kh0, ql[ds], S0);
        S0 = MFMA(kl0, qh[ds], S0);
        if (full) {
          f16x8 kh1 = ld_f16x8(khb + 8704 + ds * 32);
          f16x8 kl1 = ld_f16x8(klb + 8704 + ds * 32);
          S1 = MFMA(kh1, qh[ds], S1);
          S1 = MFMA(kh1, ql[ds], S1);
          S1 = MFMA(kl1, qh[ds], S1);
        }
      }

      // ---- causal mask (diagonal tile only) ----
      if (j == jmax) {
        #pragma unroll
        for (int r = 0; r < 16; ++r) {
          int krow = (r & 3) + 8 * (r >> 2) + 4 * lg2;
          if (j * 64 + krow > qrow) S0[r] = -1e30f;
          if (full) { if (j * 64 + 32 + krow > qrow) S1[r] = -1e30f; }
        }
      }

      // ---- online softmax (base-2); lane holds 32 k-vals of column q=l31 ----
      float tm = S0[0];
      #pragma unroll
      for (int r = 0; r < 16; ++r) tm = fmaxf(tm, S0[r]);
      if (full) {
        #pragma unroll
        for (int r = 0; r < 16; ++r) tm = fmaxf(tm, S1[r]);
      }
      tm = fmaxf(tm, __shfl_xor(tm, 32));
      float m2n = fmaxf(m2, tm);
      float fac = exp2f(m2 - m2n);
      u32 U0[8], U1[8];
      float ps = 0.0f;
      #pragma unroll
      for (int t = 0; t < 8; ++t) {
        _Float16 h0 = (_Float16)exp2f(S0[2 * t] - m2n);
        _Float16 h1 = (_Float16)exp2f(S0[2 * t + 1] - m2n);
        U0[t] = packh(h0, h1);
        ps += (float)h0 + (float)h1;
      }
      if (full) {
        #pragma unroll
        for (int t = 0; t < 8; ++t) {
          _Float16 h0 = (_Float16)exp2f(S1[2 * t] - m2n);
          _Float16 h1 = (_Float16)exp2f(S1[2 * t + 1] - m2n);
          U1[t] = packh(h0, h1);
          ps += (float)h0 + (float)h1;
        }
      } else {
        #pragma unroll
        for (int t = 0; t < 8; ++t) U1[t] = 0u;
      }
      ps += __shfl_xor(ps, 32);
      lsum = lsum * fac + ps;
      m2 = m2n;
      #pragma unroll
      for (int r = 0; r < 16; ++r) {
        int rq = (r & 3) + 8 * (r >> 2) + 4 * lg2;
        float fr = __shfl(fac, rq);
        O[0][r] *= fr; O[1][r] *= fr; O[2][r] *= fr; O[3][r] *= fr;
      }

      // ---- PV: A-fragments built in-register via permlane32_swap (T12) ----
      const unsigned char* vthb = bufc + VTH_OFF;
      const unsigned char* vtlb = bufc + VTL_OFF;
      const int swb = (l31 & 24) >> 1;
      #pragma unroll
      for (int ks = 0; ks < 4; ++ks) {
        if (ks >= 2 && !full) continue;
        u32 a0, a1, b0, b1;
        if (ks == 0)      { a0 = U0[0]; a1 = U0[1]; b0 = U0[2]; b1 = U0[3]; }
        else if (ks == 1) { a0 = U0[4]; a1 = U0[5]; b0 = U0[6]; b1 = U0[7]; }
        else if (ks == 2) { a0 = U1[0]; a1 = U1[1]; b0 = U1[2]; b1 = U1[3]; }
        else              { a0 = U1[4]; a1 = U1[5]; b0 = U1[6]; b1 = U1[7]; }
        asm("v_permlane32_swap_b32 %0, %1" : "+v"(a0), "+v"(b0));
        asm("v_permlane32_swap_b32 %0, %1" : "+v"(a1), "+v"(b1));
        u32x4 ttv; ttv.x = a0; ttv.y = a1; ttv.z = b0; ttv.w = b1;
        f16x8 pa = __builtin_bit_cast(f16x8, ttv);
        const int dwo = ks * 8 + lg2 * 4;
        #pragma unroll
        for (int n = 0; n < 4; ++n) {
          int sz = swb + ((n & 1) << 4);
          size_t off = (size_t)(32 * n + l31) * 144 + (size_t)((dwo ^ sz) * 4);
          f16x8 vh = ld_f16x8(vthb + off);
          f16x8 vl = ld_f16x8(vtlb + off);
          O[n] = MFMA(pa, vh, O[n]);
          O[n] = MFMA(pa, vl, O[n]);
        }
      }
    }

    if (more) xform(j + 1, smem + (size_t)((j + 1) & 1) * BUF_SZ);
    __syncthreads();
  }

  // ---------- epilogue ----------
  float inv = 1.0f / lsum;
  #pragma unroll
  for (int r = 0; r < 16; ++r) {
    int rq = (r & 3) + 8 * (r >> 2) + 4 * lg2;
    float fi = __shfl(inv, rq);
    int tt = qi * 256 + w * 32 + rq;
    float* orow = Og + (cbase + tt) * 2048 + hoff + l31;
    orow[0]  = O[0][r] * fi;
    orow[32] = O[1][r] * fi;
    orow[64] = O[2][r] * fi;
    orow[96] = O[3][r] * fi;
  }
}

extern "C" void kernel_launch(void* const* d_in, const int* in_sizes, int n_in,
                              void* d_out, int out_size, void* d_ws, size_t ws_size,
                              hipStream_t stream) {
  const float* q = (const float*)d_in[0];
  const float* k = (const float*)d_in[1];
  const float* v = (const float*)d_in[2];
  const int* start = (const int*)d_in[3];
  float* out = (float*)d_out;
  float* tab = (float*)d_ws;     // 4096*64*2 floats = 2 MB

  rope_table_k<<<dim3(1024), dim3(256), 0, stream>>>(start, tab);
  chunked_attn_k<<<dim3(1024), dim3(512), 0, stream>>>(q, k, v, out, tab);
}